// Round 9
// baseline (104.064 us; speedup 1.0000x reference)
//
#include <hip/hip_runtime.h>

// RelativeMultiHeadAttn: B=8 S=512 D_MODEL=1024 H=16 HD=64
// Round 8: k_attn — dbuf K/V prefetch with ONE barrier per iter, posP
//          B-frags in registers (L2-hot), additive mask, 44KB LDS -> 3/CU.
//   ws layout (bytes):
//     xh   @ 0MiB  : x cast to fp16             [4096][1024]  (8 MiB)
//     wT   @ 8MiB  : Wqv transposed fp16        [2048][1024]  (4 MiB)
//     posP @ 12MiB : [sin(t f), cos(t f)] fp16  [512][64]     (64 KiB)
//     qrr  @ 13MiB : q + r_r_bias fp16          [B,H,S,64]    (8 MiB)
//     qrwp @ 21MiB : rot(q + r_w_bias) fp16     [B,H,S,64]    (8 MiB)
//     vT   @ 29MiB : v transposed fp16          [B,H,64,S]    (8 MiB)

using h4 = __attribute__((ext_vector_type(4))) _Float16;
using h8 = __attribute__((ext_vector_type(8))) _Float16;
using f32x4 = __attribute__((ext_vector_type(4))) float;

#define MFMA16(a, b, c) __builtin_amdgcn_mfma_f32_16x16x32_f16((a), (b), (c), 0, 0, 0)

#define GLOAD_LDS16(gp, lp)                                                        \
  __builtin_amdgcn_global_load_lds(                                                \
      (const __attribute__((address_space(1))) unsigned int*)(gp),                 \
      (__attribute__((address_space(3))) unsigned int*)(lp), 16, 0, 0)

// ---- fused prep: cast x, build posP, transpose Wqv ------------------------
__global__ __launch_bounds__(256) void k_prep(const float* __restrict__ x,
                                              const float* __restrict__ Wqv,
                                              _Float16* __restrict__ xh,
                                              _Float16* __restrict__ wT,
                                              _Float16* __restrict__ posP) {
  __shared__ _Float16 t[64][72];
  int bid = blockIdx.x;
  int tid = threadIdx.x;
  if (bid < 2048) {
    size_t idx = (size_t)bid * 256 + tid;
    const float* src = x + idx * 8;
    _Float16 tmp[8];
#pragma unroll
    for (int j = 0; j < 8; ++j) tmp[j] = (_Float16)src[j];
    *(h8*)(xh + idx * 8) = *(const h8*)tmp;
  } else if (bid < 2176) {
    int idx = (bid - 2048) * 256 + tid;
    int tt = idx >> 6, j = idx & 63;
    int jj = j & 31;
    float f = expf((float)jj * (-9.210340371976184f / 31.0f));  // 10000^(-jj/31)
    float ang = (float)tt * f;
    posP[idx] = (_Float16)((j < 32) ? sinf(ang) : cosf(ang));
  } else {
    int b2 = bid - 2176;
    int bk = b2 & 15, bn = b2 >> 4;
    int k0 = bk * 64, n0 = bn * 64;
    int r = tid >> 2, c = (tid & 3) * 16;
    const float* src = Wqv + (size_t)(k0 + r) * 2048 + n0 + c;
#pragma unroll
    for (int j = 0; j < 16; ++j) t[r][c + j] = (_Float16)src[j];
    __syncthreads();
    _Float16 tmp[16];
#pragma unroll
    for (int j = 0; j < 16; ++j) tmp[j] = t[c + j][r];
    _Float16* dst = wT + (size_t)(n0 + r) * 1024 + k0 + c;
    *(h8*)dst = *(const h8*)tmp;
    *(h8*)(dst + 8) = *(const h8*)(tmp + 8);
  }
}

// ---- GEMM qv = x @ Wqv, 128x128x32, double-buffered 2-phase pipeline ------
__global__ __launch_bounds__(256) void k_gemm(const _Float16* __restrict__ xh,
                                              const _Float16* __restrict__ wT,
                                              const float* __restrict__ rr,
                                              const float* __restrict__ rw,
                                              _Float16* __restrict__ qrr,
                                              _Float16* __restrict__ qrwp,
                                              _Float16* __restrict__ vT) {
  __shared__ _Float16 At[2][128 * 32];
  __shared__ _Float16 Bt[2][128 * 32];

  int bid = blockIdx.x;
  int bm = bid & 31, bn = bid >> 5;
  int tid = threadIdx.x;
  int w = tid >> 6, lane = tid & 63;
  int lr = lane & 15, lg = lane >> 4;

  const _Float16* gA = xh + (size_t)(bm * 128 + 32 * w + (lane >> 2)) * 1024 + (lane & 3) * 8;
  const _Float16* gB = wT + (size_t)(bn * 128 + 32 * w + (lane >> 2)) * 1024 + (lane & 3) * 8;

  auto stage = [&](int bufi, int k0) {
    GLOAD_LDS16(gA + k0, &At[bufi][(32 * w) * 32]);
    GLOAD_LDS16(gA + 16 * 1024 + k0, &At[bufi][(32 * w + 16) * 32]);
    GLOAD_LDS16(gB + k0, &Bt[bufi][(32 * w) * 32]);
    GLOAD_LDS16(gB + 16 * 1024 + k0, &Bt[bufi][(32 * w + 16) * 32]);
  };

  int wm = w >> 1, wn = w & 1;
  f32x4 acc[4][4] = {};

  stage(0, 0);
  __syncthreads();
  int buf = 0;
  for (int i = 0; i < 32; ++i) {
    if (i < 31) stage(buf ^ 1, (i + 1) * 32);
    const _Float16* la = &At[buf][(wm * 64 + lr) * 32 + lg * 8];
    const _Float16* lb = &Bt[buf][(wn * 64 + lr) * 32 + lg * 8];
    h8 af[4], bf[4];
#pragma unroll
    for (int mi = 0; mi < 4; ++mi) af[mi] = *(const h8*)(la + mi * 512);
#pragma unroll
    for (int ni = 0; ni < 4; ++ni) bf[ni] = *(const h8*)(lb + ni * 512);
#pragma unroll
    for (int mi = 0; mi < 4; ++mi)
#pragma unroll
      for (int ni = 0; ni < 4; ++ni)
        acc[mi][ni] = MFMA16(af[mi], bf[ni], acc[mi][ni]);
    __syncthreads();
    buf ^= 1;
  }

  int hg = bn * 2 + wn;
  int mb = bm * 128 + wm * 64;
  if (hg < 16) {
    int h = hg;
    float rrv[4], rwv[4];
#pragma unroll
    for (int ni = 0; ni < 4; ++ni) {
      rrv[ni] = rr[h * 64 + ni * 16 + lr];
      rwv[ni] = rw[h * 64 + ni * 16 + lr];
    }
    float f0 = expf((float)lr * (-9.210340371976184f / 31.0f));
    float f1 = expf((float)(16 + lr) * (-9.210340371976184f / 31.0f));
#pragma unroll
    for (int mi = 0; mi < 4; ++mi)
#pragma unroll
      for (int r = 0; r < 4; ++r) {
        int m = mb + mi * 16 + lg * 4 + r;
        int b = m >> 9, s = m & 511;
        size_t base = ((size_t)(b * 16 + h) * 512 + s) * 64;
#pragma unroll
        for (int ni = 0; ni < 4; ++ni)
          qrr[base + ni * 16 + lr] = (_Float16)(acc[mi][ni][r] + rrv[ni]);
        {
          float qs = acc[mi][0][r] + rwv[0], qc = acc[mi][2][r] + rwv[2];
          float sn, cs;
          sincosf((float)s * f0, &sn, &cs);
          qrwp[base + lr] = (_Float16)(qs * cs + qc * sn);
          qrwp[base + lr + 32] = (_Float16)(qc * cs - qs * sn);
        }
        {
          float qs = acc[mi][1][r] + rwv[1], qc = acc[mi][3][r] + rwv[3];
          float sn, cs;
          sincosf((float)s * f1, &sn, &cs);
          qrwp[base + 16 + lr] = (_Float16)(qs * cs + qc * sn);
          qrwp[base + 16 + lr + 32] = (_Float16)(qc * cs - qs * sn);
        }
      }
  } else {
    int h = hg - 16;
#pragma unroll
    for (int mi = 0; mi < 4; ++mi) {
      int m = mb + mi * 16 + lg * 4;
      int b = m >> 9, s0 = m & 511;
      size_t vtbase = (size_t)(b * 16 + h) * 64 * 512;
#pragma unroll
      for (int ni = 0; ni < 4; ++ni) {
        int d = ni * 16 + lr;
        _Float16 t4[4];
#pragma unroll
        for (int r = 0; r < 4; ++r) t4[r] = (_Float16)acc[mi][ni][r];
        *(h4*)(vT + vtbase + (size_t)d * 512 + s0) = *(const h4*)t4;
      }
    }
  }
}

// ---- flash attention: one block per (b, h, 64-row q-block) ----------------
// Decode: qb = bid>>7 -> all 8 q-blocks of one (b,h) share bid mod 8 (XCD).
// Per 64-wide KV tile: K and V^T double-buffered in LDS (global_load_lds,
// XOR-swizzled source chunks, linear dest, swizzled reads); posP B-frags
// loaded to REGISTERS from global (L2-hot, shared by all blocks). One
// barrier per iteration (end sync drains the prefetch, which issued at the
// iteration top and hid under scores+softmax+PV).
__global__ __launch_bounds__(256, 3) void k_attn(const _Float16* __restrict__ xh,
                                                 const _Float16* __restrict__ qrr,
                                                 const _Float16* __restrict__ qrwp,
                                                 const _Float16* __restrict__ vT,
                                                 const _Float16* __restrict__ posPg,
                                                 const int* __restrict__ mask,
                                                 float* __restrict__ out) {
  __shared__ _Float16 Kp[2][64 * 64];   // [t][d]   2 x 8 KiB
  __shared__ _Float16 Vt[2][64 * 64];   // [d][t]   2 x 8 KiB
  __shared__ _Float16 Pl[4][16 * 72];   // per-wave P tile  9 KiB
  __shared__ float Ma[512];             // additive mask    2 KiB

  int bid = blockIdx.x;
  int qb = bid >> 7, h = bid & 15, b = (bid >> 4) & 7;
  int q0 = qb * 64;
  int tid = threadIdx.x;
  int w = tid >> 6, lane = tid & 63;
  int lr = lane & 15, lg = lane >> 4;

  const size_t bh = (size_t)(b * 16 + h);
  const _Float16* qrr_p = qrr + (bh * 512 + q0 + 16 * w + lr) * 64 + lg * 8;
  const _Float16* qrw_p = qrwp + (bh * 512 + q0 + 16 * w + lr) * 64 + lg * 8;
  const _Float16* kb = xh + (size_t)b * 512 * 1024 + h * 64;
  const _Float16* vTp = vT + bh * 64 * 512;
  const int* mrow = mask + b * 512;

  // stage a 64x64 K tile: 512 chunks, wave w does [w*128, w*128+128)
  auto stageK = [&](int bufi, int t0s) {
#pragma unroll
    for (int it = 0; it < 2; ++it) {
      int a = w * 128 + it * 64 + lane;
      int trow = a >> 3, c8 = a & 7;
      int c8s = c8 ^ (trow & 7);
      GLOAD_LDS16(kb + (size_t)(t0s + trow) * 1024 + c8s * 8,
                  &Kp[bufi][(w * 128 + it * 64) * 8]);
    }
  };
  auto stageV = [&](int bufi, int t0s) {
#pragma unroll
    for (int it = 0; it < 2; ++it) {
      int a = w * 128 + it * 64 + lane;
      int drow = a >> 3, c8 = a & 7;
      int c8s = c8 ^ (drow & 7);
      GLOAD_LDS16(vTp + (size_t)drow * 512 + t0s + c8s * 8,
                  &Vt[bufi][(w * 128 + it * 64) * 8]);
    }
  };

  Ma[tid] = (1.f - (float)mrow[tid]) * -1e8f;
  Ma[tid + 256] = (1.f - (float)mrow[tid + 256]) * -1e8f;

  // Hoist A-fragments (same for every k-tile).
  h8 ar0 = *(const h8*)(qrr_p);
  h8 ar1 = *(const h8*)(qrr_p + 32);
  h8 aw0 = *(const h8*)(qrw_p);
  h8 aw1 = *(const h8*)(qrw_p + 32);

  float m_run[4], l_run[4];
  f32x4 O[4];  // O[df][r]
#pragma unroll
  for (int r = 0; r < 4; ++r) { m_run[r] = -1e30f; l_run[r] = 0.f; }
#pragma unroll
  for (int df = 0; df < 4; ++df) O[df] = (f32x4){0.f, 0.f, 0.f, 0.f};

  _Float16* pw = &Pl[w][0];

  stageK(0, 0);
  stageV(0, 0);
  __syncthreads();  // prologue stage + Ma drained
  int buf = 0;
  for (int i = 0; i < 8; ++i) {
    int t0 = i * 64;

    // posP B-frags -> registers (issued first; stage gloads follow, so the
    // compiler's counted vmcnt covers pp before MFMA without draining stage)
    h8 pp0[4], pp1[4];
#pragma unroll
    for (int tf = 0; tf < 4; ++tf) {
      const _Float16* pp = posPg + (size_t)(t0 + tf * 16 + lr) * 64 + lg * 8;
      pp0[tf] = *(const h8*)pp;
      pp1[tf] = *(const h8*)(pp + 32);
    }
    if (i < 7) {  // prefetch next K/V tile under this iteration's compute
      stageK(buf ^ 1, t0 + 64);
      stageV(buf ^ 1, t0 + 64);
    }

    // ---- scores s[tf][r] (row = lg*4+r, col = tf*16+lr) -------------------
    float s[4][4];
#pragma unroll
    for (int tf = 0; tf < 4; ++tf) {
      int row = tf * 16 + lr;
      const _Float16* bp = &Kp[buf][row * 64];
      int p = lr & 7;
      h8 b0 = *(const h8*)(bp + ((0 + lg) ^ p) * 8);
      h8 b1 = *(const h8*)(bp + ((4 + lg) ^ p) * 8);
      f32x4 c = {0.f, 0.f, 0.f, 0.f};
      c = MFMA16(ar0, b0, c);
      c = MFMA16(ar1, b1, c);
      c = MFMA16(aw0, pp0[tf], c);
      c = MFMA16(aw1, pp1[tf], c);
      float ma = Ma[t0 + tf * 16 + lr];
#pragma unroll
      for (int r = 0; r < 4; ++r) s[tf][r] = c[r] + ma;
    }

    // ---- online softmax (reduce across the 16 lanes holding each row) -----
#pragma unroll
    for (int r = 0; r < 4; ++r) {
      float rm = fmaxf(fmaxf(s[0][r], s[1][r]), fmaxf(s[2][r], s[3][r]));
#pragma unroll
      for (int d = 1; d < 16; d <<= 1) rm = fmaxf(rm, __shfl_xor(rm, d));
      float mn = fmaxf(m_run[r], rm);
      float sc = __expf(m_run[r] - mn);
      m_run[r] = mn;
      float rs = 0.f;
#pragma unroll
      for (int tf = 0; tf < 4; ++tf) {
        float p = __expf(s[tf][r] - mn);
        _Float16 p16 = (_Float16)p;
        pw[(lg * 4 + r) * 72 + tf * 16 + lr] = p16;
        rs += (float)p16;  // accumulate rounded value for PV consistency
      }
#pragma unroll
      for (int d = 1; d < 16; d <<= 1) rs += __shfl_xor(rs, d);
      l_run[r] = l_run[r] * sc + rs;
#pragma unroll
      for (int df = 0; df < 4; ++df) O[df][r] *= sc;
    }

    // ---- PV: P (wave-private LDS, same-wave in-order) as A; V from LDS ----
    h8 pa0 = *(const h8*)(pw + lr * 72 + lg * 8);
    h8 pa1 = *(const h8*)(pw + lr * 72 + 32 + lg * 8);
#pragma unroll
    for (int df = 0; df < 4; ++df) {
      int row = df * 16 + lr;
      const _Float16* vbp = &Vt[buf][row * 64];
      int p = lr & 7;
      h8 vb0 = *(const h8*)(vbp + ((0 + lg) ^ p) * 8);
      h8 vb1 = *(const h8*)(vbp + ((4 + lg) ^ p) * 8);
      O[df] = MFMA16(pa0, vb0, O[df]);
      O[df] = MFMA16(pa1, vb1, O[df]);
    }
    __syncthreads();  // drains vmcnt(0): prefetch landed; buf reads done
    buf ^= 1;
  }

  // ---- epilogue: normalize and store
#pragma unroll
  for (int df = 0; df < 4; ++df)
#pragma unroll
    for (int r = 0; r < 4; ++r) {
      int ii = 16 * w + lg * 4 + r;
      out[((size_t)b * 512 + q0 + ii) * 1024 + h * 64 + df * 16 + lr] = O[df][r] / l_run[r];
    }
}

extern "C" void kernel_launch(void* const* d_in, const int* in_sizes, int n_in,
                              void* d_out, int out_size, void* d_ws, size_t ws_size,
                              hipStream_t stream) {
  const float* x = (const float*)d_in[0];
  const int* mask = (const int*)d_in[1];
  const float* Wqv = (const float*)d_in[2];
  const float* rr = (const float*)d_in[3];
  const float* rw = (const float*)d_in[4];
  float* out = (float*)d_out;
  char* ws = (char*)d_ws;
  const size_t MB = 1024 * 1024;
  _Float16* xh = (_Float16*)(ws);
  _Float16* wT = (_Float16*)(ws + 8 * MB);
  _Float16* posP = (_Float16*)(ws + 12 * MB);
  _Float16* qrr = (_Float16*)(ws + 13 * MB);
  _Float16* qrwp = (_Float16*)(ws + 21 * MB);
  _Float16* vT = (_Float16*)(ws + 29 * MB);

  k_prep<<<2688, 256, 0, stream>>>(x, Wqv, xh, wT, posP);
  k_gemm<<<512, 256, 0, stream>>>(xh, wT, rr, rw, qrr, qrwp, vT);
  k_attn<<<1024, 256, 0, stream>>>(xh, qrr, qrwp, vT, posP, mask, out);
}

// Round 10
// 78.733 us; speedup vs baseline: 1.3217x; 1.3217x over previous
//
#include <hip/hip_runtime.h>

// RelativeMultiHeadAttn: B=8 S=512 D_MODEL=1024 H=16 HD=64
// Round 9: k_attn = R6 structure (staged [K|posP]+V^T, 128-wide tiles,
//          2 barriers/tile) with QBLK=128: each wave owns TWO 16-row q-groups
//          processed sequentially -> 2x MFMA per staged tile, grid 512
//          (exactly 2 blocks/CU, co-resident), staged traffic halved.
//   ws layout (bytes):
//     xh   @ 0MiB  : x cast to fp16             [4096][1024]  (8 MiB)
//     wT   @ 8MiB  : Wqv transposed fp16        [2048][1024]  (4 MiB)
//     posP @ 12MiB : [sin(t f), cos(t f)] fp16  [512][64]     (64 KiB)
//     qrr  @ 13MiB : q + r_r_bias fp16          [B,H,S,64]    (8 MiB)
//     qrwp @ 21MiB : rot(q + r_w_bias) fp16     [B,H,S,64]    (8 MiB)
//     vT   @ 29MiB : v transposed fp16          [B,H,64,S]    (8 MiB)

using h4 = __attribute__((ext_vector_type(4))) _Float16;
using h8 = __attribute__((ext_vector_type(8))) _Float16;
using f32x4 = __attribute__((ext_vector_type(4))) float;

#define MFMA16(a, b, c) __builtin_amdgcn_mfma_f32_16x16x32_f16((a), (b), (c), 0, 0, 0)

#define GLOAD_LDS16(gp, lp)                                                        \
  __builtin_amdgcn_global_load_lds(                                                \
      (const __attribute__((address_space(1))) unsigned int*)(gp),                 \
      (__attribute__((address_space(3))) unsigned int*)(lp), 16, 0, 0)

// ---- fused prep: cast x, build posP, transpose Wqv ------------------------
__global__ __launch_bounds__(256) void k_prep(const float* __restrict__ x,
                                              const float* __restrict__ Wqv,
                                              _Float16* __restrict__ xh,
                                              _Float16* __restrict__ wT,
                                              _Float16* __restrict__ posP) {
  __shared__ _Float16 t[64][72];
  int bid = blockIdx.x;
  int tid = threadIdx.x;
  if (bid < 2048) {
    size_t idx = (size_t)bid * 256 + tid;
    const float* src = x + idx * 8;
    _Float16 tmp[8];
#pragma unroll
    for (int j = 0; j < 8; ++j) tmp[j] = (_Float16)src[j];
    *(h8*)(xh + idx * 8) = *(const h8*)tmp;
  } else if (bid < 2176) {
    int idx = (bid - 2048) * 256 + tid;
    int tt = idx >> 6, j = idx & 63;
    int jj = j & 31;
    float f = expf((float)jj * (-9.210340371976184f / 31.0f));  // 10000^(-jj/31)
    float ang = (float)tt * f;
    posP[idx] = (_Float16)((j < 32) ? sinf(ang) : cosf(ang));
  } else {
    int b2 = bid - 2176;
    int bk = b2 & 15, bn = b2 >> 4;
    int k0 = bk * 64, n0 = bn * 64;
    int r = tid >> 2, c = (tid & 3) * 16;
    const float* src = Wqv + (size_t)(k0 + r) * 2048 + n0 + c;
#pragma unroll
    for (int j = 0; j < 16; ++j) t[r][c + j] = (_Float16)src[j];
    __syncthreads();
    _Float16 tmp[16];
#pragma unroll
    for (int j = 0; j < 16; ++j) tmp[j] = t[c + j][r];
    _Float16* dst = wT + (size_t)(n0 + r) * 1024 + k0 + c;
    *(h8*)dst = *(const h8*)tmp;
    *(h8*)(dst + 8) = *(const h8*)(tmp + 8);
  }
}

// ---- GEMM qv = x @ Wqv, 128x128x32, double-buffered 2-phase pipeline ------
__global__ __launch_bounds__(256) void k_gemm(const _Float16* __restrict__ xh,
                                              const _Float16* __restrict__ wT,
                                              const float* __restrict__ rr,
                                              const float* __restrict__ rw,
                                              _Float16* __restrict__ qrr,
                                              _Float16* __restrict__ qrwp,
                                              _Float16* __restrict__ vT) {
  __shared__ _Float16 At[2][128 * 32];
  __shared__ _Float16 Bt[2][128 * 32];

  int bid = blockIdx.x;
  int bm = bid & 31, bn = bid >> 5;
  int tid = threadIdx.x;
  int w = tid >> 6, lane = tid & 63;
  int lr = lane & 15, lg = lane >> 4;

  const _Float16* gA = xh + (size_t)(bm * 128 + 32 * w + (lane >> 2)) * 1024 + (lane & 3) * 8;
  const _Float16* gB = wT + (size_t)(bn * 128 + 32 * w + (lane >> 2)) * 1024 + (lane & 3) * 8;

  auto stage = [&](int bufi, int k0) {
    GLOAD_LDS16(gA + k0, &At[bufi][(32 * w) * 32]);
    GLOAD_LDS16(gA + 16 * 1024 + k0, &At[bufi][(32 * w + 16) * 32]);
    GLOAD_LDS16(gB + k0, &Bt[bufi][(32 * w) * 32]);
    GLOAD_LDS16(gB + 16 * 1024 + k0, &Bt[bufi][(32 * w + 16) * 32]);
  };

  int wm = w >> 1, wn = w & 1;
  f32x4 acc[4][4] = {};

  stage(0, 0);
  __syncthreads();
  int buf = 0;
  for (int i = 0; i < 32; ++i) {
    if (i < 31) stage(buf ^ 1, (i + 1) * 32);
    const _Float16* la = &At[buf][(wm * 64 + lr) * 32 + lg * 8];
    const _Float16* lb = &Bt[buf][(wn * 64 + lr) * 32 + lg * 8];
    h8 af[4], bf[4];
#pragma unroll
    for (int mi = 0; mi < 4; ++mi) af[mi] = *(const h8*)(la + mi * 512);
#pragma unroll
    for (int ni = 0; ni < 4; ++ni) bf[ni] = *(const h8*)(lb + ni * 512);
#pragma unroll
    for (int mi = 0; mi < 4; ++mi)
#pragma unroll
      for (int ni = 0; ni < 4; ++ni)
        acc[mi][ni] = MFMA16(af[mi], bf[ni], acc[mi][ni]);
    __syncthreads();
    buf ^= 1;
  }

  int hg = bn * 2 + wn;
  int mb = bm * 128 + wm * 64;
  if (hg < 16) {
    int h = hg;
    float rrv[4], rwv[4];
#pragma unroll
    for (int ni = 0; ni < 4; ++ni) {
      rrv[ni] = rr[h * 64 + ni * 16 + lr];
      rwv[ni] = rw[h * 64 + ni * 16 + lr];
    }
    float f0 = expf((float)lr * (-9.210340371976184f / 31.0f));
    float f1 = expf((float)(16 + lr) * (-9.210340371976184f / 31.0f));
#pragma unroll
    for (int mi = 0; mi < 4; ++mi)
#pragma unroll
      for (int r = 0; r < 4; ++r) {
        int m = mb + mi * 16 + lg * 4 + r;
        int b = m >> 9, s = m & 511;
        size_t base = ((size_t)(b * 16 + h) * 512 + s) * 64;
#pragma unroll
        for (int ni = 0; ni < 4; ++ni)
          qrr[base + ni * 16 + lr] = (_Float16)(acc[mi][ni][r] + rrv[ni]);
        {
          float qs = acc[mi][0][r] + rwv[0], qc = acc[mi][2][r] + rwv[2];
          float sn, cs;
          sincosf((float)s * f0, &sn, &cs);
          qrwp[base + lr] = (_Float16)(qs * cs + qc * sn);
          qrwp[base + lr + 32] = (_Float16)(qc * cs - qs * sn);
        }
        {
          float qs = acc[mi][1][r] + rwv[1], qc = acc[mi][3][r] + rwv[3];
          float sn, cs;
          sincosf((float)s * f1, &sn, &cs);
          qrwp[base + 16 + lr] = (_Float16)(qs * cs + qc * sn);
          qrwp[base + 16 + lr + 32] = (_Float16)(qc * cs - qs * sn);
        }
      }
  } else {
    int h = hg - 16;
#pragma unroll
    for (int mi = 0; mi < 4; ++mi) {
      int m = mb + mi * 16 + lg * 4;
      int b = m >> 9, s0 = m & 511;
      size_t vtbase = (size_t)(b * 16 + h) * 64 * 512;
#pragma unroll
      for (int ni = 0; ni < 4; ++ni) {
        int d = ni * 16 + lr;
        _Float16 t4[4];
#pragma unroll
        for (int r = 0; r < 4; ++r) t4[r] = (_Float16)acc[mi][ni][r];
        *(h4*)(vT + vtbase + (size_t)d * 512 + s0) = *(const h4*)t4;
      }
    }
  }
}

// ---- flash attention: one block per (b, h, 128-row q-block) ---------------
// Decode: qb = bid>>7 -> all 4 q-blocks of one (b,h) share bid mod 8 (XCD).
// R6 pipeline: per 128-wide KV tile stage Kp[128][128]=[K|posP] and
// Vt[64][128] to LDS (global_load_lds, XOR-swizzled source, linear dest,
// swizzled reads); each wave processes TWO 16-row q-groups sequentially,
// reusing its P strip (same-wave in-order LDS). 2 barriers per tile.
__global__ __launch_bounds__(256, 2) void k_attn(const _Float16* __restrict__ xh,
                                                 const _Float16* __restrict__ qrr,
                                                 const _Float16* __restrict__ qrwp,
                                                 const _Float16* __restrict__ vT,
                                                 const _Float16* __restrict__ posPg,
                                                 const int* __restrict__ mask,
                                                 float* __restrict__ out) {
  __shared__ _Float16 Kp[128 * 128];    // [t][K(0:64)|posP(0:64)]  32 KiB
  __shared__ _Float16 Vt[64 * 128];     // [d][t]                   16 KiB
  __shared__ _Float16 Pl[4][16 * 136];  // per-wave P strip          17 KiB
  __shared__ float Ma[512];             // additive mask              2 KiB

  int bid = blockIdx.x;
  int qb = bid >> 7, h = bid & 15, b = (bid >> 4) & 7;
  int q0 = qb * 128;
  int tid = threadIdx.x;
  int w = tid >> 6, lane = tid & 63;
  int lr = lane & 15, lg = lane >> 4;

  const size_t bh = (size_t)(b * 16 + h);
  const _Float16* kb = xh + (size_t)b * 512 * 1024 + h * 64;
  const _Float16* vTp = vT + bh * 64 * 512;
  const int* mrow = mask + b * 512;

  // stage one 128-wide tile: Kp 2048 chunks (8/wave-iter), Vt 1024 (4/wave-iter)
  auto stage = [&](int t0s) {
#pragma unroll
    for (int it = 0; it < 8; ++it) {
      int a = w * 512 + it * 64 + lane;
      int trow = a >> 4, c16 = a & 15;
      int c16s = c16 ^ (trow & 15);
      const _Float16* g = (c16s < 8)
          ? kb + (size_t)(t0s + trow) * 1024 + c16s * 8
          : posPg + (size_t)(t0s + trow) * 64 + (c16s - 8) * 8;
      GLOAD_LDS16(g, &Kp[(size_t)(w * 512 + it * 64) * 8]);
    }
#pragma unroll
    for (int it = 0; it < 4; ++it) {
      int a = w * 256 + it * 64 + lane;
      int drow = a >> 4, c16 = a & 15;
      int c16s = c16 ^ (drow & 15);
      const _Float16* g = vTp + (size_t)drow * 512 + t0s + c16s * 8;
      GLOAD_LDS16(g, &Vt[(size_t)(w * 256 + it * 64) * 8]);
    }
  };

  Ma[tid] = (1.f - (float)mrow[tid]) * -1e8f;
  Ma[tid + 256] = (1.f - (float)mrow[tid + 256]) * -1e8f;

  // Hoist A-fragments for both row groups (rows q0 + 32w + 16rg + lr).
  h8 ar0[2], ar1[2], aw0[2], aw1[2];
#pragma unroll
  for (int rg = 0; rg < 2; ++rg) {
    const _Float16* qrr_p = qrr + (bh * 512 + q0 + 32 * w + 16 * rg + lr) * 64 + lg * 8;
    const _Float16* qrw_p = qrwp + (bh * 512 + q0 + 32 * w + 16 * rg + lr) * 64 + lg * 8;
    ar0[rg] = *(const h8*)(qrr_p);
    ar1[rg] = *(const h8*)(qrr_p + 32);
    aw0[rg] = *(const h8*)(qrw_p);
    aw1[rg] = *(const h8*)(qrw_p + 32);
  }

  float m_run[2][4], l_run[2][4];
  f32x4 O[2][4];  // O[rg][df]
#pragma unroll
  for (int rg = 0; rg < 2; ++rg)
#pragma unroll
    for (int r = 0; r < 4; ++r) {
      m_run[rg][r] = -1e30f;
      l_run[rg][r] = 0.f;
      O[rg][r] = (f32x4){0.f, 0.f, 0.f, 0.f};
    }

  _Float16* pw = &Pl[w][0];

  for (int t0 = 0; t0 < 512; t0 += 128) {
    stage(t0);
    __syncthreads();  // drains vmcnt -> tile (and Ma on first iter) ready

#pragma unroll
    for (int rg = 0; rg < 2; ++rg) {
      // ---- scores s[tf][r] (row = lg*4+r, col = tf*16+lr): K=128 from LDS -
      float s[8][4];
#pragma unroll
      for (int tf = 0; tf < 8; ++tf) {
        int row = tf * 16 + lr;  // row & 15 == lr
        const _Float16* bp = &Kp[row * 128];
        h8 b0 = *(const h8*)(bp + ((0 + lg) ^ lr) * 8);
        h8 b1 = *(const h8*)(bp + ((4 + lg) ^ lr) * 8);
        h8 b2 = *(const h8*)(bp + ((8 + lg) ^ lr) * 8);
        h8 b3 = *(const h8*)(bp + ((12 + lg) ^ lr) * 8);
        f32x4 c = {0.f, 0.f, 0.f, 0.f};
        c = MFMA16(ar0[rg], b0, c);
        c = MFMA16(ar1[rg], b1, c);
        c = MFMA16(aw0[rg], b2, c);
        c = MFMA16(aw1[rg], b3, c);
        float ma = Ma[t0 + tf * 16 + lr];
#pragma unroll
        for (int r = 0; r < 4; ++r) s[tf][r] = c[r] + ma;
      }

      // ---- online softmax (reduce across the 16 lanes holding each row) ---
#pragma unroll
      for (int r = 0; r < 4; ++r) {
        float rm = s[0][r];
#pragma unroll
        for (int tf = 1; tf < 8; ++tf) rm = fmaxf(rm, s[tf][r]);
#pragma unroll
        for (int d = 1; d < 16; d <<= 1) rm = fmaxf(rm, __shfl_xor(rm, d));
        float mn = fmaxf(m_run[rg][r], rm);
        float sc = __expf(m_run[rg][r] - mn);
        m_run[rg][r] = mn;
        float rs = 0.f;
#pragma unroll
        for (int tf = 0; tf < 8; ++tf) {
          float p = __expf(s[tf][r] - mn);
          _Float16 p16 = (_Float16)p;
          pw[(lg * 4 + r) * 136 + tf * 16 + lr] = p16;
          rs += (float)p16;  // accumulate rounded value for PV consistency
        }
#pragma unroll
        for (int d = 1; d < 16; d <<= 1) rs += __shfl_xor(rs, d);
        l_run[rg][r] = l_run[rg][r] * sc + rs;
#pragma unroll
        for (int df = 0; df < 4; ++df) O[rg][df][r] *= sc;
      }

      // ---- PV: P (wave-private strip, same-wave in-order) as A; V as B ----
      h8 pa[4];
#pragma unroll
      for (int ks = 0; ks < 4; ++ks)
        pa[ks] = *(const h8*)(pw + lr * 136 + ks * 32 + lg * 8);
#pragma unroll
      for (int df = 0; df < 4; ++df) {
        int row = df * 16 + lr;  // row & 15 == lr
        const _Float16* vbp = &Vt[row * 128];
#pragma unroll
        for (int ks = 0; ks < 4; ++ks) {
          h8 vb = *(const h8*)(vbp + ((ks * 4 + lg) ^ lr) * 8);
          O[rg][df] = MFMA16(pa[ks], vb, O[rg][df]);
        }
      }
    }
    __syncthreads();  // all LDS reads done before next tile's staging
  }

  // ---- epilogue: normalize and store
#pragma unroll
  for (int rg = 0; rg < 2; ++rg)
#pragma unroll
    for (int df = 0; df < 4; ++df)
#pragma unroll
      for (int r = 0; r < 4; ++r) {
        int ii = 32 * w + 16 * rg + lg * 4 + r;
        out[((size_t)b * 512 + q0 + ii) * 1024 + h * 64 + df * 16 + lr] =
            O[rg][df][r] / l_run[rg][r];
      }
}

extern "C" void kernel_launch(void* const* d_in, const int* in_sizes, int n_in,
                              void* d_out, int out_size, void* d_ws, size_t ws_size,
                              hipStream_t stream) {
  const float* x = (const float*)d_in[0];
  const int* mask = (const int*)d_in[1];
  const float* Wqv = (const float*)d_in[2];
  const float* rr = (const float*)d_in[3];
  const float* rw = (const float*)d_in[4];
  float* out = (float*)d_out;
  char* ws = (char*)d_ws;
  const size_t MB = 1024 * 1024;
  _Float16* xh = (_Float16*)(ws);
  _Float16* wT = (_Float16*)(ws + 8 * MB);
  _Float16* posP = (_Float16*)(ws + 12 * MB);
  _Float16* qrr = (_Float16*)(ws + 13 * MB);
  _Float16* qrwp = (_Float16*)(ws + 21 * MB);
  _Float16* vT = (_Float16*)(ws + 29 * MB);

  k_prep<<<2688, 256, 0, stream>>>(x, Wqv, xh, wT, posP);
  k_gemm<<<512, 256, 0, stream>>>(xh, wT, rr, rw, qrr, qrwp, vT);
  k_attn<<<512, 256, 0, stream>>>(xh, qrr, qrwp, vT, posP, mask, out);
}

// Round 11
// 72.232 us; speedup vs baseline: 1.4407x; 1.0900x over previous
//
#include <hip/hip_runtime.h>

// RelativeMultiHeadAttn: B=8 S=512 D_MODEL=1024 H=16 HD=64
// Round 10: k_gemm BK=64 (half the barriers, XOR-swizzled LDS) +
//           __sincosf epilogue; k_attn exp2 softmax (pre-scaled q by log2e)
//           + setprio around MFMA clusters. Attn structure = R9 (passed).
//   ws layout (bytes):
//     xh   @ 0MiB  : x cast to fp16             [4096][1024]  (8 MiB)
//     wT   @ 8MiB  : Wqv transposed fp16        [2048][1024]  (4 MiB)
//     posP @ 12MiB : [sin(t f), cos(t f)] fp16  [512][64]     (64 KiB)
//     qrr  @ 13MiB : (q + r_r_bias)*log2e fp16  [B,H,S,64]    (8 MiB)
//     qrwp @ 21MiB : rot(q + r_w_bias)*log2e    [B,H,S,64]    (8 MiB)
//     vT   @ 29MiB : v transposed fp16          [B,H,64,S]    (8 MiB)

using h4 = __attribute__((ext_vector_type(4))) _Float16;
using h8 = __attribute__((ext_vector_type(8))) _Float16;
using f32x4 = __attribute__((ext_vector_type(4))) float;

#define MFMA16(a, b, c) __builtin_amdgcn_mfma_f32_16x16x32_f16((a), (b), (c), 0, 0, 0)

#define GLOAD_LDS16(gp, lp)                                                        \
  __builtin_amdgcn_global_load_lds(                                                \
      (const __attribute__((address_space(1))) unsigned int*)(gp),                 \
      (__attribute__((address_space(3))) unsigned int*)(lp), 16, 0, 0)

#define L2E 1.4426950408889634f

// ---- fused prep: cast x, build posP, transpose Wqv ------------------------
__global__ __launch_bounds__(256) void k_prep(const float* __restrict__ x,
                                              const float* __restrict__ Wqv,
                                              _Float16* __restrict__ xh,
                                              _Float16* __restrict__ wT,
                                              _Float16* __restrict__ posP) {
  __shared__ _Float16 t[64][72];
  int bid = blockIdx.x;
  int tid = threadIdx.x;
  if (bid < 2048) {
    size_t idx = (size_t)bid * 256 + tid;
    const float* src = x + idx * 8;
    _Float16 tmp[8];
#pragma unroll
    for (int j = 0; j < 8; ++j) tmp[j] = (_Float16)src[j];
    *(h8*)(xh + idx * 8) = *(const h8*)tmp;
  } else if (bid < 2176) {
    int idx = (bid - 2048) * 256 + tid;
    int tt = idx >> 6, j = idx & 63;
    int jj = j & 31;
    float f = expf((float)jj * (-9.210340371976184f / 31.0f));  // 10000^(-jj/31)
    float ang = (float)tt * f;
    posP[idx] = (_Float16)((j < 32) ? sinf(ang) : cosf(ang));
  } else {
    int b2 = bid - 2176;
    int bk = b2 & 15, bn = b2 >> 4;
    int k0 = bk * 64, n0 = bn * 64;
    int r = tid >> 2, c = (tid & 3) * 16;
    const float* src = Wqv + (size_t)(k0 + r) * 2048 + n0 + c;
#pragma unroll
    for (int j = 0; j < 16; ++j) t[r][c + j] = (_Float16)src[j];
    __syncthreads();
    _Float16 tmp[16];
#pragma unroll
    for (int j = 0; j < 16; ++j) tmp[j] = t[c + j][r];
    _Float16* dst = wT + (size_t)(n0 + r) * 1024 + k0 + c;
    *(h8*)dst = *(const h8*)tmp;
    *(h8*)(dst + 8) = *(const h8*)(tmp + 8);
  }
}

// ---- GEMM qv = x @ Wqv, 128x128x64, double-buffered, XOR-swizzled LDS -----
__global__ __launch_bounds__(256) void k_gemm(const _Float16* __restrict__ xh,
                                              const _Float16* __restrict__ wT,
                                              const float* __restrict__ rr,
                                              const float* __restrict__ rw,
                                              _Float16* __restrict__ qrr,
                                              _Float16* __restrict__ qrwp,
                                              _Float16* __restrict__ vT) {
  __shared__ _Float16 At[2][128 * 64];  // 2 x 16 KiB
  __shared__ _Float16 Bt[2][128 * 64];  // 2 x 16 KiB

  int bid = blockIdx.x;
  int bm = bid & 31, bn = bid >> 5;
  int tid = threadIdx.x;
  int w = tid >> 6, lane = tid & 63;
  int lr = lane & 15, lg = lane >> 4;

  // stage a 128x64 tile pair; source chunk XOR-swizzled, LDS dest linear.
  auto stage = [&](int bufi, int k0) {
#pragma unroll
    for (int it = 0; it < 4; ++it) {
      int a = w * 256 + it * 64 + lane;
      int trow = a >> 3, c8s = (a & 7) ^ (trow & 7);
      GLOAD_LDS16(xh + (size_t)(bm * 128 + trow) * 1024 + k0 + c8s * 8,
                  &At[bufi][a * 8]);
    }
#pragma unroll
    for (int it = 0; it < 4; ++it) {
      int a = w * 256 + it * 64 + lane;
      int trow = a >> 3, c8s = (a & 7) ^ (trow & 7);
      GLOAD_LDS16(wT + (size_t)(bn * 128 + trow) * 1024 + k0 + c8s * 8,
                  &Bt[bufi][a * 8]);
    }
  };

  int wm = w >> 1, wn = w & 1;
  f32x4 acc[4][4] = {};

  stage(0, 0);
  __syncthreads();
  int buf = 0;
  for (int i = 0; i < 16; ++i) {
    if (i < 15) stage(buf ^ 1, (i + 1) * 64);
#pragma unroll
    for (int kk = 0; kk < 2; ++kk) {
      h8 af[4], bf[4];
#pragma unroll
      for (int mi = 0; mi < 4; ++mi) {
        int row = wm * 64 + mi * 16 + lr;
        af[mi] = *(const h8*)(&At[buf][row * 64 + (((kk * 4 + lg) ^ (lr & 7)) * 8)]);
      }
#pragma unroll
      for (int ni = 0; ni < 4; ++ni) {
        int row = wn * 64 + ni * 16 + lr;
        bf[ni] = *(const h8*)(&Bt[buf][row * 64 + (((kk * 4 + lg) ^ (lr & 7)) * 8)]);
      }
#pragma unroll
      for (int mi = 0; mi < 4; ++mi)
#pragma unroll
        for (int ni = 0; ni < 4; ++ni)
          acc[mi][ni] = MFMA16(af[mi], bf[ni], acc[mi][ni]);
    }
    __syncthreads();
    buf ^= 1;
  }

  int hg = bn * 2 + wn;
  int mb = bm * 128 + wm * 64;
  if (hg < 16) {
    int h = hg;
    float rrv[4], rwv[4];
#pragma unroll
    for (int ni = 0; ni < 4; ++ni) {
      rrv[ni] = rr[h * 64 + ni * 16 + lr];
      rwv[ni] = rw[h * 64 + ni * 16 + lr];
    }
    float f0 = expf((float)lr * (-9.210340371976184f / 31.0f));
    float f1 = expf((float)(16 + lr) * (-9.210340371976184f / 31.0f));
#pragma unroll
    for (int mi = 0; mi < 4; ++mi)
#pragma unroll
      for (int r = 0; r < 4; ++r) {
        int m = mb + mi * 16 + lg * 4 + r;
        int b = m >> 9, s = m & 511;
        size_t base = ((size_t)(b * 16 + h) * 512 + s) * 64;
#pragma unroll
        for (int ni = 0; ni < 4; ++ni)
          qrr[base + ni * 16 + lr] = (_Float16)((acc[mi][ni][r] + rrv[ni]) * L2E);
        {
          float qs = acc[mi][0][r] + rwv[0], qc = acc[mi][2][r] + rwv[2];
          float sn, cs;
          __sincosf((float)s * f0, &sn, &cs);
          qrwp[base + lr] = (_Float16)((qs * cs + qc * sn) * L2E);
          qrwp[base + lr + 32] = (_Float16)((qc * cs - qs * sn) * L2E);
        }
        {
          float qs = acc[mi][1][r] + rwv[1], qc = acc[mi][3][r] + rwv[3];
          float sn, cs;
          __sincosf((float)s * f1, &sn, &cs);
          qrwp[base + 16 + lr] = (_Float16)((qs * cs + qc * sn) * L2E);
          qrwp[base + 16 + lr + 32] = (_Float16)((qc * cs - qs * sn) * L2E);
        }
      }
  } else {
    int h = hg - 16;
#pragma unroll
    for (int mi = 0; mi < 4; ++mi) {
      int m = mb + mi * 16 + lg * 4;
      int b = m >> 9, s0 = m & 511;
      size_t vtbase = (size_t)(b * 16 + h) * 64 * 512;
#pragma unroll
      for (int ni = 0; ni < 4; ++ni) {
        int d = ni * 16 + lr;
        _Float16 t4[4];
#pragma unroll
        for (int r = 0; r < 4; ++r) t4[r] = (_Float16)acc[mi][ni][r];
        *(h4*)(vT + vtbase + (size_t)d * 512 + s0) = *(const h4*)t4;
      }
    }
  }
}

// ---- flash attention: one block per (b, h, 128-row q-block) ---------------
// R9 structure: stage Kp[128][128]=[K|posP] + Vt[64][128] per 128-wide tile
// (global_load_lds, XOR-swizzled source, linear dest, swizzled reads);
// each wave runs TWO 16-row q-groups off the staged tile. Scores are in
// log2e-scaled space -> softmax uses exp2f directly. setprio(1) around
// MFMA clusters (T5).
__global__ __launch_bounds__(256, 2) void k_attn(const _Float16* __restrict__ xh,
                                                 const _Float16* __restrict__ qrr,
                                                 const _Float16* __restrict__ qrwp,
                                                 const _Float16* __restrict__ vT,
                                                 const _Float16* __restrict__ posPg,
                                                 const int* __restrict__ mask,
                                                 float* __restrict__ out) {
  __shared__ _Float16 Kp[128 * 128];    // 32 KiB
  __shared__ _Float16 Vt[64 * 128];     // 16 KiB
  __shared__ _Float16 Pl[4][16 * 136];  // per-wave P strip  17 KiB
  __shared__ float Ma[512];             // additive mask (log2e-scaled)

  int bid = blockIdx.x;
  int qb = bid >> 7, h = bid & 15, b = (bid >> 4) & 7;
  int q0 = qb * 128;
  int tid = threadIdx.x;
  int w = tid >> 6, lane = tid & 63;
  int lr = lane & 15, lg = lane >> 4;

  const size_t bh = (size_t)(b * 16 + h);
  const _Float16* kb = xh + (size_t)b * 512 * 1024 + h * 64;
  const _Float16* vTp = vT + bh * 64 * 512;
  const int* mrow = mask + b * 512;

  auto stage = [&](int t0s) {
#pragma unroll
    for (int it = 0; it < 8; ++it) {
      int a = w * 512 + it * 64 + lane;
      int trow = a >> 4, c16 = a & 15;
      int c16s = c16 ^ (trow & 15);
      const _Float16* g = (c16s < 8)
          ? kb + (size_t)(t0s + trow) * 1024 + c16s * 8
          : posPg + (size_t)(t0s + trow) * 64 + (c16s - 8) * 8;
      GLOAD_LDS16(g, &Kp[(size_t)(w * 512 + it * 64) * 8]);
    }
#pragma unroll
    for (int it = 0; it < 4; ++it) {
      int a = w * 256 + it * 64 + lane;
      int drow = a >> 4, c16 = a & 15;
      int c16s = c16 ^ (drow & 15);
      const _Float16* g = vTp + (size_t)drow * 512 + t0s + c16s * 8;
      GLOAD_LDS16(g, &Vt[(size_t)(w * 256 + it * 64) * 8]);
    }
  };

  Ma[tid] = (1.f - (float)mrow[tid]) * -1.4426950e8f;
  Ma[tid + 256] = (1.f - (float)mrow[tid + 256]) * -1.4426950e8f;

  // Hoist A-fragments for both row groups (rows q0 + 32w + 16rg + lr).
  h8 ar0[2], ar1[2], aw0[2], aw1[2];
#pragma unroll
  for (int rg = 0; rg < 2; ++rg) {
    const _Float16* qrr_p = qrr + (bh * 512 + q0 + 32 * w + 16 * rg + lr) * 64 + lg * 8;
    const _Float16* qrw_p = qrwp + (bh * 512 + q0 + 32 * w + 16 * rg + lr) * 64 + lg * 8;
    ar0[rg] = *(const h8*)(qrr_p);
    ar1[rg] = *(const h8*)(qrr_p + 32);
    aw0[rg] = *(const h8*)(qrw_p);
    aw1[rg] = *(const h8*)(qrw_p + 32);
  }

  float m_run[2][4], l_run[2][4];
  f32x4 O[2][4];
#pragma unroll
  for (int rg = 0; rg < 2; ++rg)
#pragma unroll
    for (int r = 0; r < 4; ++r) {
      m_run[rg][r] = -1e30f;
      l_run[rg][r] = 0.f;
      O[rg][r] = (f32x4){0.f, 0.f, 0.f, 0.f};
    }

  _Float16* pw = &Pl[w][0];

  for (int t0 = 0; t0 < 512; t0 += 128) {
    stage(t0);
    __syncthreads();  // drains vmcnt -> tile (and Ma on first iter) ready

#pragma unroll
    for (int rg = 0; rg < 2; ++rg) {
      // ---- scores s[tf][r] (row = lg*4+r, col = tf*16+lr): K=128 from LDS -
      float s[8][4];
      __builtin_amdgcn_s_setprio(1);
#pragma unroll
      for (int tf = 0; tf < 8; ++tf) {
        int row = tf * 16 + lr;  // row & 15 == lr
        const _Float16* bp = &Kp[row * 128];
        h8 b0 = *(const h8*)(bp + ((0 + lg) ^ lr) * 8);
        h8 b1 = *(const h8*)(bp + ((4 + lg) ^ lr) * 8);
        h8 b2 = *(const h8*)(bp + ((8 + lg) ^ lr) * 8);
        h8 b3 = *(const h8*)(bp + ((12 + lg) ^ lr) * 8);
        f32x4 c = {0.f, 0.f, 0.f, 0.f};
        c = MFMA16(ar0[rg], b0, c);
        c = MFMA16(ar1[rg], b1, c);
        c = MFMA16(aw0[rg], b2, c);
        c = MFMA16(aw1[rg], b3, c);
        float ma = Ma[t0 + tf * 16 + lr];
#pragma unroll
        for (int r = 0; r < 4; ++r) s[tf][r] = c[r] + ma;
      }
      __builtin_amdgcn_s_setprio(0);

      // ---- online softmax in log2 space (16-lane row reduce) --------------
#pragma unroll
      for (int r = 0; r < 4; ++r) {
        float rm = s[0][r];
#pragma unroll
        for (int tf = 1; tf < 8; ++tf) rm = fmaxf(rm, s[tf][r]);
#pragma unroll
        for (int d = 1; d < 16; d <<= 1) rm = fmaxf(rm, __shfl_xor(rm, d));
        float mn = fmaxf(m_run[rg][r], rm);
        float sc = exp2f(m_run[rg][r] - mn);
        m_run[rg][r] = mn;
        float rs = 0.f;
#pragma unroll
        for (int tf = 0; tf < 8; ++tf) {
          float p = exp2f(s[tf][r] - mn);
          _Float16 p16 = (_Float16)p;
          pw[(lg * 4 + r) * 136 + tf * 16 + lr] = p16;
          rs += (float)p16;  // accumulate rounded value for PV consistency
        }
#pragma unroll
        for (int d = 1; d < 16; d <<= 1) rs += __shfl_xor(rs, d);
        l_run[rg][r] = l_run[rg][r] * sc + rs;
#pragma unroll
        for (int df = 0; df < 4; ++df) O[rg][df][r] *= sc;
      }

      // ---- PV: P (wave-private strip, same-wave in-order) as A; V as B ----
      h8 pa[4];
#pragma unroll
      for (int ks = 0; ks < 4; ++ks)
        pa[ks] = *(const h8*)(pw + lr * 136 + ks * 32 + lg * 8);
      __builtin_amdgcn_s_setprio(1);
#pragma unroll
      for (int df = 0; df < 4; ++df) {
        int row = df * 16 + lr;  // row & 15 == lr
        const _Float16* vbp = &Vt[row * 128];
#pragma unroll
        for (int ks = 0; ks < 4; ++ks) {
          h8 vb = *(const h8*)(vbp + ((ks * 4 + lg) ^ lr) * 8);
          O[rg][df] = MFMA16(pa[ks], vb, O[rg][df]);
        }
      }
      __builtin_amdgcn_s_setprio(0);
    }
    __syncthreads();  // all LDS reads done before next tile's staging
  }

  // ---- epilogue: normalize and store
#pragma unroll
  for (int rg = 0; rg < 2; ++rg)
#pragma unroll
    for (int df = 0; df < 4; ++df)
#pragma unroll
      for (int r = 0; r < 4; ++r) {
        int ii = 32 * w + 16 * rg + lg * 4 + r;
        out[((size_t)b * 512 + q0 + ii) * 1024 + h * 64 + df * 16 + lr] =
            O[rg][df][r] / l_run[rg][r];
      }
}

extern "C" void kernel_launch(void* const* d_in, const int* in_sizes, int n_in,
                              void* d_out, int out_size, void* d_ws, size_t ws_size,
                              hipStream_t stream) {
  const float* x = (const float*)d_in[0];
  const int* mask = (const int*)d_in[1];
  const float* Wqv = (const float*)d_in[2];
  const float* rr = (const float*)d_in[3];
  const float* rw = (const float*)d_in[4];
  float* out = (float*)d_out;
  char* ws = (char*)d_ws;
  const size_t MB = 1024 * 1024;
  _Float16* xh = (_Float16*)(ws);
  _Float16* wT = (_Float16*)(ws + 8 * MB);
  _Float16* posP = (_Float16*)(ws + 12 * MB);
  _Float16* qrr = (_Float16*)(ws + 13 * MB);
  _Float16* qrwp = (_Float16*)(ws + 21 * MB);
  _Float16* vT = (_Float16*)(ws + 29 * MB);

  k_prep<<<2688, 256, 0, stream>>>(x, Wqv, xh, wT, posP);
  k_gemm<<<512, 256, 0, stream>>>(xh, wT, rr, rw, qrr, qrwp, vT);
  k_attn<<<512, 256, 0, stream>>>(xh, qrr, qrwp, vT, posP, mask, out);
}

// Round 12
// 67.994 us; speedup vs baseline: 1.5305x; 1.0623x over previous
//
#include <hip/hip_runtime.h>

// RelativeMultiHeadAttn: B=8 S=512 D_MODEL=1024 H=16 HD=64
// Round 11: k_attn swapped QK^T (scores = mfma(K,Q) -> S[t][q], q lane-local)
//           => in-lane softmax reductions, b64 P writes, defer-max (THR=8).
//           gemm/prep = R10 (passed).
//   ws layout (bytes):
//     xh   @ 0MiB  : x cast to fp16             [4096][1024]  (8 MiB)
//     wT   @ 8MiB  : Wqv transposed fp16        [2048][1024]  (4 MiB)
//     posP @ 12MiB : [sin(t f), cos(t f)] fp16  [512][64]     (64 KiB)
//     qrr  @ 13MiB : (q + r_r_bias)*log2e fp16  [B,H,S,64]    (8 MiB)
//     qrwp @ 21MiB : rot(q + r_w_bias)*log2e    [B,H,S,64]    (8 MiB)
//     vT   @ 29MiB : v transposed fp16          [B,H,64,S]    (8 MiB)

using h4 = __attribute__((ext_vector_type(4))) _Float16;
using h8 = __attribute__((ext_vector_type(8))) _Float16;
using f32x4 = __attribute__((ext_vector_type(4))) float;

#define MFMA16(a, b, c) __builtin_amdgcn_mfma_f32_16x16x32_f16((a), (b), (c), 0, 0, 0)

#define GLOAD_LDS16(gp, lp)                                                        \
  __builtin_amdgcn_global_load_lds(                                                \
      (const __attribute__((address_space(1))) unsigned int*)(gp),                 \
      (__attribute__((address_space(3))) unsigned int*)(lp), 16, 0, 0)

#define L2E 1.4426950408889634f

// ---- fused prep: cast x, build posP, transpose Wqv ------------------------
__global__ __launch_bounds__(256) void k_prep(const float* __restrict__ x,
                                              const float* __restrict__ Wqv,
                                              _Float16* __restrict__ xh,
                                              _Float16* __restrict__ wT,
                                              _Float16* __restrict__ posP) {
  __shared__ _Float16 t[64][72];
  int bid = blockIdx.x;
  int tid = threadIdx.x;
  if (bid < 2048) {
    size_t idx = (size_t)bid * 256 + tid;
    const float* src = x + idx * 8;
    _Float16 tmp[8];
#pragma unroll
    for (int j = 0; j < 8; ++j) tmp[j] = (_Float16)src[j];
    *(h8*)(xh + idx * 8) = *(const h8*)tmp;
  } else if (bid < 2176) {
    int idx = (bid - 2048) * 256 + tid;
    int tt = idx >> 6, j = idx & 63;
    int jj = j & 31;
    float f = expf((float)jj * (-9.210340371976184f / 31.0f));  // 10000^(-jj/31)
    float ang = (float)tt * f;
    posP[idx] = (_Float16)((j < 32) ? sinf(ang) : cosf(ang));
  } else {
    int b2 = bid - 2176;
    int bk = b2 & 15, bn = b2 >> 4;
    int k0 = bk * 64, n0 = bn * 64;
    int r = tid >> 2, c = (tid & 3) * 16;
    const float* src = Wqv + (size_t)(k0 + r) * 2048 + n0 + c;
#pragma unroll
    for (int j = 0; j < 16; ++j) t[r][c + j] = (_Float16)src[j];
    __syncthreads();
    _Float16 tmp[16];
#pragma unroll
    for (int j = 0; j < 16; ++j) tmp[j] = t[c + j][r];
    _Float16* dst = wT + (size_t)(n0 + r) * 1024 + k0 + c;
    *(h8*)dst = *(const h8*)tmp;
    *(h8*)(dst + 8) = *(const h8*)(tmp + 8);
  }
}

// ---- GEMM qv = x @ Wqv, 128x128x64, double-buffered, XOR-swizzled LDS -----
__global__ __launch_bounds__(256) void k_gemm(const _Float16* __restrict__ xh,
                                              const _Float16* __restrict__ wT,
                                              const float* __restrict__ rr,
                                              const float* __restrict__ rw,
                                              _Float16* __restrict__ qrr,
                                              _Float16* __restrict__ qrwp,
                                              _Float16* __restrict__ vT) {
  __shared__ _Float16 At[2][128 * 64];  // 2 x 16 KiB
  __shared__ _Float16 Bt[2][128 * 64];  // 2 x 16 KiB

  int bid = blockIdx.x;
  int bm = bid & 31, bn = bid >> 5;
  int tid = threadIdx.x;
  int w = tid >> 6, lane = tid & 63;
  int lr = lane & 15, lg = lane >> 4;

  auto stage = [&](int bufi, int k0) {
#pragma unroll
    for (int it = 0; it < 4; ++it) {
      int a = w * 256 + it * 64 + lane;
      int trow = a >> 3, c8s = (a & 7) ^ (trow & 7);
      GLOAD_LDS16(xh + (size_t)(bm * 128 + trow) * 1024 + k0 + c8s * 8,
                  &At[bufi][a * 8]);
    }
#pragma unroll
    for (int it = 0; it < 4; ++it) {
      int a = w * 256 + it * 64 + lane;
      int trow = a >> 3, c8s = (a & 7) ^ (trow & 7);
      GLOAD_LDS16(wT + (size_t)(bn * 128 + trow) * 1024 + k0 + c8s * 8,
                  &Bt[bufi][a * 8]);
    }
  };

  int wm = w >> 1, wn = w & 1;
  f32x4 acc[4][4] = {};

  stage(0, 0);
  __syncthreads();
  int buf = 0;
  for (int i = 0; i < 16; ++i) {
    if (i < 15) stage(buf ^ 1, (i + 1) * 64);
#pragma unroll
    for (int kk = 0; kk < 2; ++kk) {
      h8 af[4], bf[4];
#pragma unroll
      for (int mi = 0; mi < 4; ++mi) {
        int row = wm * 64 + mi * 16 + lr;
        af[mi] = *(const h8*)(&At[buf][row * 64 + (((kk * 4 + lg) ^ (lr & 7)) * 8)]);
      }
#pragma unroll
      for (int ni = 0; ni < 4; ++ni) {
        int row = wn * 64 + ni * 16 + lr;
        bf[ni] = *(const h8*)(&Bt[buf][row * 64 + (((kk * 4 + lg) ^ (lr & 7)) * 8)]);
      }
#pragma unroll
      for (int mi = 0; mi < 4; ++mi)
#pragma unroll
        for (int ni = 0; ni < 4; ++ni)
          acc[mi][ni] = MFMA16(af[mi], bf[ni], acc[mi][ni]);
    }
    __syncthreads();
    buf ^= 1;
  }

  int hg = bn * 2 + wn;
  int mb = bm * 128 + wm * 64;
  if (hg < 16) {
    int h = hg;
    float rrv[4], rwv[4];
#pragma unroll
    for (int ni = 0; ni < 4; ++ni) {
      rrv[ni] = rr[h * 64 + ni * 16 + lr];
      rwv[ni] = rw[h * 64 + ni * 16 + lr];
    }
    float f0 = expf((float)lr * (-9.210340371976184f / 31.0f));
    float f1 = expf((float)(16 + lr) * (-9.210340371976184f / 31.0f));
#pragma unroll
    for (int mi = 0; mi < 4; ++mi)
#pragma unroll
      for (int r = 0; r < 4; ++r) {
        int m = mb + mi * 16 + lg * 4 + r;
        int b = m >> 9, s = m & 511;
        size_t base = ((size_t)(b * 16 + h) * 512 + s) * 64;
#pragma unroll
        for (int ni = 0; ni < 4; ++ni)
          qrr[base + ni * 16 + lr] = (_Float16)((acc[mi][ni][r] + rrv[ni]) * L2E);
        {
          float qs = acc[mi][0][r] + rwv[0], qc = acc[mi][2][r] + rwv[2];
          float sn, cs;
          __sincosf((float)s * f0, &sn, &cs);
          qrwp[base + lr] = (_Float16)((qs * cs + qc * sn) * L2E);
          qrwp[base + lr + 32] = (_Float16)((qc * cs - qs * sn) * L2E);
        }
        {
          float qs = acc[mi][1][r] + rwv[1], qc = acc[mi][3][r] + rwv[3];
          float sn, cs;
          __sincosf((float)s * f1, &sn, &cs);
          qrwp[base + 16 + lr] = (_Float16)((qs * cs + qc * sn) * L2E);
          qrwp[base + 16 + lr + 32] = (_Float16)((qc * cs - qs * sn) * L2E);
        }
      }
  } else {
    int h = hg - 16;
#pragma unroll
    for (int mi = 0; mi < 4; ++mi) {
      int m = mb + mi * 16 + lg * 4;
      int b = m >> 9, s0 = m & 511;
      size_t vtbase = (size_t)(b * 16 + h) * 64 * 512;
#pragma unroll
      for (int ni = 0; ni < 4; ++ni) {
        int d = ni * 16 + lr;
        _Float16 t4[4];
#pragma unroll
        for (int r = 0; r < 4; ++r) t4[r] = (_Float16)acc[mi][ni][r];
        *(h4*)(vT + vtbase + (size_t)d * 512 + s0) = *(const h4*)t4;
      }
    }
  }
}

// ---- flash attention: one block per (b, h, 128-row q-block) ---------------
// Staging = R9/R10 (Kp=[K|posP], Vt, XOR-swizzled). NEW: scores computed
// SWAPPED (mfma(K_frag, Q_frag)) so C = S[t][q] with q = lane&15 lane-local:
// softmax max/sum are in-lane trees + 2 shfl_xor; P written as b64 chunks
// into the same pw[q*136+t] layout (PV unchanged); defer-max skips O-rescale
// when the running max grows by <8 (log2 space).
__global__ __launch_bounds__(256, 2) void k_attn(const _Float16* __restrict__ xh,
                                                 const _Float16* __restrict__ qrr,
                                                 const _Float16* __restrict__ qrwp,
                                                 const _Float16* __restrict__ vT,
                                                 const _Float16* __restrict__ posPg,
                                                 const int* __restrict__ mask,
                                                 float* __restrict__ out) {
  __shared__ _Float16 Kp[128 * 128];    // 32 KiB
  __shared__ _Float16 Vt[64 * 128];     // 16 KiB
  __shared__ _Float16 Pl[4][16 * 136];  // per-wave P strip  17 KiB
  __shared__ float Ma[512];             // additive mask (log2e-scaled)

  int bid = blockIdx.x;
  int qb = bid >> 7, h = bid & 15, b = (bid >> 4) & 7;
  int q0 = qb * 128;
  int tid = threadIdx.x;
  int w = tid >> 6, lane = tid & 63;
  int lr = lane & 15, lg = lane >> 4;

  const size_t bh = (size_t)(b * 16 + h);
  const _Float16* kb = xh + (size_t)b * 512 * 1024 + h * 64;
  const _Float16* vTp = vT + bh * 64 * 512;
  const int* mrow = mask + b * 512;

  auto stage = [&](int t0s) {
#pragma unroll
    for (int it = 0; it < 8; ++it) {
      int a = w * 512 + it * 64 + lane;
      int trow = a >> 4, c16 = a & 15;
      int c16s = c16 ^ (trow & 15);
      const _Float16* g = (c16s < 8)
          ? kb + (size_t)(t0s + trow) * 1024 + c16s * 8
          : posPg + (size_t)(t0s + trow) * 64 + (c16s - 8) * 8;
      GLOAD_LDS16(g, &Kp[(size_t)(w * 512 + it * 64) * 8]);
    }
#pragma unroll
    for (int it = 0; it < 4; ++it) {
      int a = w * 256 + it * 64 + lane;
      int drow = a >> 4, c16 = a & 15;
      int c16s = c16 ^ (drow & 15);
      const _Float16* g = vTp + (size_t)drow * 512 + t0s + c16s * 8;
      GLOAD_LDS16(g, &Vt[(size_t)(w * 256 + it * 64) * 8]);
    }
  };

  Ma[tid] = (1.f - (float)mrow[tid]) * -1.4426950e8f;
  Ma[tid + 256] = (1.f - (float)mrow[tid + 256]) * -1.4426950e8f;

  // Hoist Q-fragments for both row groups (rows q0 + 32w + 16rg + lr).
  h8 ar0[2], ar1[2], aw0[2], aw1[2];
#pragma unroll
  for (int rg = 0; rg < 2; ++rg) {
    const _Float16* qrr_p = qrr + (bh * 512 + q0 + 32 * w + 16 * rg + lr) * 64 + lg * 8;
    const _Float16* qrw_p = qrwp + (bh * 512 + q0 + 32 * w + 16 * rg + lr) * 64 + lg * 8;
    ar0[rg] = *(const h8*)(qrr_p);
    ar1[rg] = *(const h8*)(qrr_p + 32);
    aw0[rg] = *(const h8*)(qrw_p);
    aw1[rg] = *(const h8*)(qrw_p + 32);
  }

  float m_run[2] = {-1e30f, -1e30f}, l_run[2] = {0.f, 0.f};
  f32x4 O[2][4];
#pragma unroll
  for (int rg = 0; rg < 2; ++rg)
#pragma unroll
    for (int df = 0; df < 4; ++df) O[rg][df] = (f32x4){0.f, 0.f, 0.f, 0.f};

  _Float16* pw = &Pl[w][0];

  for (int t0 = 0; t0 < 512; t0 += 128) {
    stage(t0);
    __syncthreads();  // drains vmcnt -> tile (and Ma on first iter) ready

#pragma unroll
    for (int rg = 0; rg < 2; ++rg) {
      // ---- scores SWAPPED: s[tf][r] = S[t = t0+tf*16+lg*4+r][q = lr] ------
      float s[8][4];
      __builtin_amdgcn_s_setprio(1);
#pragma unroll
      for (int tf = 0; tf < 8; ++tf) {
        int row = tf * 16 + lr;  // row & 15 == lr
        const _Float16* bp = &Kp[row * 128];
        h8 b0 = *(const h8*)(bp + ((0 + lg) ^ lr) * 8);
        h8 b1 = *(const h8*)(bp + ((4 + lg) ^ lr) * 8);
        h8 b2 = *(const h8*)(bp + ((8 + lg) ^ lr) * 8);
        h8 b3 = *(const h8*)(bp + ((12 + lg) ^ lr) * 8);
        f32x4 c = {0.f, 0.f, 0.f, 0.f};
        c = MFMA16(b0, ar0[rg], c);  // A = K-rows (t), B = Q-rows (q)
        c = MFMA16(b1, ar1[rg], c);
        c = MFMA16(b2, aw0[rg], c);
        c = MFMA16(b3, aw1[rg], c);
        f32x4 mav = *(const f32x4*)&Ma[t0 + tf * 16 + lg * 4];
#pragma unroll
        for (int r = 0; r < 4; ++r) s[tf][r] = c[r] + mav[r];
      }
      __builtin_amdgcn_s_setprio(0);

      // ---- softmax (q = lr lane-local): in-lane trees + 2 cross-lg shfl ---
      float rm = s[0][0];
#pragma unroll
      for (int tf = 0; tf < 8; ++tf)
#pragma unroll
        for (int r = 0; r < 4; ++r) rm = fmaxf(rm, s[tf][r]);
      rm = fmaxf(rm, __shfl_xor(rm, 16));
      rm = fmaxf(rm, __shfl_xor(rm, 32));

      if (!__all(rm - m_run[rg] <= 8.f)) {  // defer-max (THR=8, log2 space)
        float mn = fmaxf(m_run[rg], rm);
        float sc = exp2f(m_run[rg] - mn);
        m_run[rg] = mn;
        l_run[rg] *= sc;
        float scq[4];
#pragma unroll
        for (int r = 0; r < 4; ++r) scq[r] = __shfl(sc, lg * 4 + r);
#pragma unroll
        for (int df = 0; df < 4; ++df)
#pragma unroll
          for (int r = 0; r < 4; ++r) O[rg][df][r] *= scq[r];
      }

      float rs = 0.f;
#pragma unroll
      for (int tf = 0; tf < 8; ++tf) {
        _Float16 p4[4];
#pragma unroll
        for (int r = 0; r < 4; ++r) {
          float p = exp2f(s[tf][r] - m_run[rg]);
          p4[r] = (_Float16)p;
          rs += (float)p4[r];  // accumulate rounded value for PV consistency
        }
        *(h4*)(pw + lr * 136 + tf * 16 + lg * 4) = *(const h4*)p4;  // b64
      }
      rs += __shfl_xor(rs, 16);
      rs += __shfl_xor(rs, 32);
      l_run[rg] += rs;

      // ---- PV: P (wave-private strip, same-wave in-order) as A; V as B ----
      h8 pa[4];
#pragma unroll
      for (int ks = 0; ks < 4; ++ks)
        pa[ks] = *(const h8*)(pw + lr * 136 + ks * 32 + lg * 8);
      __builtin_amdgcn_s_setprio(1);
#pragma unroll
      for (int df = 0; df < 4; ++df) {
        int row = df * 16 + lr;  // row & 15 == lr
        const _Float16* vbp = &Vt[row * 128];
#pragma unroll
        for (int ks = 0; ks < 4; ++ks) {
          h8 vb = *(const h8*)(vbp + ((ks * 4 + lg) ^ lr) * 8);
          O[rg][df] = MFMA16(pa[ks], vb, O[rg][df]);
        }
      }
      __builtin_amdgcn_s_setprio(0);
    }
    __syncthreads();  // all LDS reads done before next tile's staging
  }

  // ---- epilogue: broadcast l to O layout, normalize, store
#pragma unroll
  for (int rg = 0; rg < 2; ++rg) {
    float lq[4];
#pragma unroll
    for (int r = 0; r < 4; ++r) lq[r] = __shfl(l_run[rg], lg * 4 + r);
#pragma unroll
    for (int df = 0; df < 4; ++df)
#pragma unroll
      for (int r = 0; r < 4; ++r) {
        int ii = 32 * w + 16 * rg + lg * 4 + r;
        out[((size_t)b * 512 + q0 + ii) * 1024 + h * 64 + df * 16 + lr] =
            O[rg][df][r] / lq[r];
      }
  }
}

extern "C" void kernel_launch(void* const* d_in, const int* in_sizes, int n_in,
                              void* d_out, int out_size, void* d_ws, size_t ws_size,
                              hipStream_t stream) {
  const float* x = (const float*)d_in[0];
  const int* mask = (const int*)d_in[1];
  const float* Wqv = (const float*)d_in[2];
  const float* rr = (const float*)d_in[3];
  const float* rw = (const float*)d_in[4];
  float* out = (float*)d_out;
  char* ws = (char*)d_ws;
  const size_t MB = 1024 * 1024;
  _Float16* xh = (_Float16*)(ws);
  _Float16* wT = (_Float16*)(ws + 8 * MB);
  _Float16* posP = (_Float16*)(ws + 12 * MB);
  _Float16* qrr = (_Float16*)(ws + 13 * MB);
  _Float16* qrwp = (_Float16*)(ws + 21 * MB);
  _Float16* vT = (_Float16*)(ws + 29 * MB);

  k_prep<<<2688, 256, 0, stream>>>(x, Wqv, xh, wT, posP);
  k_gemm<<<512, 256, 0, stream>>>(xh, wT, rr, rw, qrr, qrwp, vT);
  k_attn<<<512, 256, 0, stream>>>(xh, qrr, qrwp, vT, posP, mask, out);
}